// Round 8
// baseline (363.120 us; speedup 1.0000x reference)
//
#include <hip/hip_runtime.h>
#include <hip/hip_bf16.h>

#define BATCH 8
#define NPTS  131072
#define DIM   32
#define NLAB  33
#define G1X   256             // pass1 blocks per batch -> 2048 blocks, 512 pts each
#define P1PTS 512
#define BPB2  128             // pass2 blocks per batch

// ws float layout
#define OFF_CNT   0                                   // gcnt: BATCH*NLAB = 264
#define OFF_SUM   264                                 // gsum: BATCH*NLAB*DIM = 8448
#define OFF_PULL  (264 + 8448)                        // pull partials: BATCH*BPB2 = 1024
#define OFF_PSUM  (OFF_PULL + BATCH * BPB2)           // pass1 sum partials: 8*256*1056
#define OFF_PCNT  (OFF_PSUM + BATCH * G1X * NLAB * DIM)  // pass1 cnt partials: 8*256*33
#define WS_FLOATS (OFF_PCNT + BATCH * G1X * NLAB)

typedef short  bf16x8 __attribute__((ext_vector_type(8)));
typedef float  f32x4  __attribute__((ext_vector_type(4)));

// Pass 1 (R12): LDS-atomic histogram, NO MFMA / NO shuffle / NO cvt.
// Post-mortem R7/R10/R11: three structurally different one-hot-GEMM
// implementations all landed at ~70us (3x the 22us BW floor) -> the shared
// machinery (label bpermute -> one-hot build -> f32->bf16 cvt -> MFMA
// dependent chain + lockstep waits) was the limiter, not staging/atomics.
// NLAB*DIM is only 4.4KB: accumulate directly with ds_add_f32 (atomicAdd on
// __shared__ float = fire-and-forget, no dependent consumer, no lgkmcnt).
// s_hist stride 33 -> bank (lab + 4*lane8)%32: ~2 lanes/bank (free).
// Loads: proven asm-volatile 2-deep pipeline (32 in flight per thread).
// 8 threads per point (lane8 = dim quad), 32 points per block-round.
#define P1_ISSUE(EB, LB, SR)                                                  \
  {                                                                           \
    _Pragma("unroll")                                                         \
    for (int j = 0; j < 8; ++j) {                                             \
      const int ve = ve0 + ((SR) * 8 + j) * 4096;                             \
      const int vl = vl0 + ((SR) * 8 + j) * 128;                              \
      asm volatile("global_load_dwordx4 %0, %1, %2"                           \
                   : "=&v"(EB[j]) : "v"(ve), "s"(ebase));                     \
      asm volatile("global_load_dword %0, %1, %2"                             \
                   : "=&v"(LB[j]) : "v"(vl), "s"(lbase));                     \
    }                                                                         \
  }

#define P1_ACCUM(EB, LB)                                                      \
  {                                                                           \
    _Pragma("unroll")                                                         \
    for (int j = 0; j < 8; ++j) {                                             \
      const int lb = LB[j];                                                   \
      float* hp = s_hist + lb * 33 + lane8 * 4;                               \
      atomicAdd(hp + 0, EB[j][0]);                                            \
      atomicAdd(hp + 1, EB[j][1]);                                            \
      atomicAdd(hp + 2, EB[j][2]);                                            \
      atomicAdd(hp + 3, EB[j][3]);                                            \
      if (lane8 == 0) atomicAdd(&s_cnt[lb], 1);                               \
    }                                                                         \
  }

__global__ __launch_bounds__(256) void pass1_kernel(
    const float* __restrict__ emb, const int* __restrict__ lab,
    float* __restrict__ psum, float* __restrict__ pcnt) {
  const int b     = blockIdx.y;
  const int tid   = threadIdx.x;
  const int sub   = tid >> 3;     // point slot 0..31 within a round
  const int lane8 = tid & 7;      // dim quad

  __shared__ float s_hist[NLAB * 33];   // stride 33: bank spread + 4.3 KB
  __shared__ int   s_cnt[NLAB];

  for (int i = tid; i < NLAB * 33; i += 256) s_hist[i] = 0.f;
  if (tid < NLAB) s_cnt[tid] = 0;
  __syncthreads();

  const size_t base = (size_t)b * NPTS + (size_t)blockIdx.x * P1PTS;
  const float* ebase = emb + base * DIM;
  const int*   lbase = lab + base;
  const int ve0 = sub * 128 + lane8 * 16;   // byte voffset: point sub, dim quad
  const int vl0 = sub * 4;

  f32x4 eA[8], eB[8];
  int   lA[8], lB[8];

  // 2 super-rounds of 8 rounds (32 points/round): issue both, counted waits.
  P1_ISSUE(eA, lA, 0);
  P1_ISSUE(eB, lB, 1);
  asm volatile("s_waitcnt vmcnt(16)" ::: "memory");   // super-round A complete
  __builtin_amdgcn_sched_barrier(0);
  P1_ACCUM(eA, lA);
  asm volatile("s_waitcnt vmcnt(0)" ::: "memory");    // super-round B complete
  __builtin_amdgcn_sched_barrier(0);
  P1_ACCUM(eB, lB);

  __syncthreads();

  // plain coalesced partial stores (no global atomics)
  const size_t pb = (size_t)b * G1X + blockIdx.x;
  for (int i = tid; i < NLAB * DIM; i += 256) {
    const int l = i >> 5, d = i & 31;
    psum[pb * (NLAB * DIM) + i] = s_hist[l * 33 + d];
  }
  if (tid < NLAB) pcnt[pb * NLAB + tid] = (float)s_cnt[tid];
}

// Folds per-block partials into gsum/gcnt. 8-way sliced over blockIdx.y
// (each slice sums G1X/8=32 partials, coalesced; 8 atomics per address).
__global__ __launch_bounds__(256) void reduce_kernel(
    const float* __restrict__ psum, const float* __restrict__ pcnt,
    float* __restrict__ gsum, float* __restrict__ gcnt) {
  constexpr int TOT = BATCH * NLAB * DIM;   // 8448
  constexpr int KS  = G1X / 8;              // 32 partials per slice
  const int slice = blockIdx.y;
  const int o = blockIdx.x * 256 + threadIdx.x;
  if (o < TOT) {
    const int b = o / (NLAB * DIM), i = o - b * (NLAB * DIM);
    const float* src = psum + ((size_t)b * G1X + slice * KS) * (NLAB * DIM) + i;
    float a0 = 0.f, a1 = 0.f, a2 = 0.f, a3 = 0.f;
#pragma unroll
    for (int k = 0; k < KS; k += 4) {
      a0 += src[(size_t)(k + 0) * (NLAB * DIM)];
      a1 += src[(size_t)(k + 1) * (NLAB * DIM)];
      a2 += src[(size_t)(k + 2) * (NLAB * DIM)];
      a3 += src[(size_t)(k + 3) * (NLAB * DIM)];
    }
    atomicAdd(&gsum[o], (a0 + a1) + (a2 + a3));
  } else if (o - TOT < BATCH * NLAB) {
    const int o2 = o - TOT;
    const int b = o2 / NLAB, l = o2 - b * NLAB;
    const float* src = pcnt + ((size_t)b * G1X + slice * KS) * NLAB + l;
    float a = 0.f;
#pragma unroll
    for (int k = 0; k < KS; ++k) a += src[(size_t)k * NLAB];
    atomicAdd(&gcnt[o2], a);
  }
}

// Pass 2: per-point hinge, streaming pipeline, NO ATOMICS. (unchanged R9)
#define CN 8                       // points per chunk
#define P2_ISSUE(LB, EB, C)                                                   \
  {                                                                           \
    _Pragma("unroll")                                                         \
    for (int j = 0; j < CN; ++j) {                                            \
      const size_t it = (size_t)(C) * CN + j;                                 \
      const unsigned long long al =                                           \
          (unsigned long long)(lab + base + p0 + it * PSTRIDE);               \
      asm volatile("global_load_dword %0, %1, off" : "=&v"(LB[j]) : "v"(al)); \
    }                                                                         \
    _Pragma("unroll")                                                         \
    for (int j = 0; j < CN; ++j) {                                            \
      const size_t it = (size_t)(C) * CN + j;                                 \
      const unsigned long long ae =                                           \
          (unsigned long long)(emb + (base + p0 + it * PSTRIDE) * DIM + d0);  \
      asm volatile("global_load_dwordx4 %0, %1, off" : "=&v"(EB[j]) : "v"(ae)); \
    }                                                                         \
  }

#define P2_COMPUTE(LB, EB)                                                    \
  {                                                                           \
    float s[CN];                                                              \
    _Pragma("unroll")                                                         \
    for (int j = 0; j < CN; ++j) {                                            \
      const f32x4 mv = *(const f32x4*)(s_mean + LB[j] * 36 + d0);             \
      const float dx = EB[j][0] - mv[0], dy = EB[j][1] - mv[1];               \
      const float dz = EB[j][2] - mv[2], dw = EB[j][3] - mv[3];               \
      s[j] = dx * dx + dy * dy + dz * dz + dw * dw;                           \
    }                                                                         \
    _Pragma("unroll")                                                         \
    for (int j = 0; j < CN; ++j) {                                            \
      s[j] += __shfl_xor(s[j], 1);                                            \
      s[j] += __shfl_xor(s[j], 2);                                            \
      s[j] += __shfl_xor(s[j], 4);                                            \
    }                                                                         \
    float sv = s[0];                                                          \
    int   lv = LB[0];                                                         \
    _Pragma("unroll")                                                         \
    for (int j = 1; j < CN; ++j) {                                            \
      sv = (lane8 == j) ? s[j] : sv;                                          \
      lv = (lane8 == j) ? LB[j] : lv;                                         \
    }                                                                         \
    const float dist = sqrtf(sv + 1e-24f);                                    \
    wacc += s_w[lv] * fmaxf(dist - 0.1f, 0.f);                                \
  }

__global__ __launch_bounds__(256, 4) void pass2_kernel(
    const float* __restrict__ emb, const int* __restrict__ lab,
    const float* __restrict__ gsum, const float* __restrict__ gcnt,
    float* __restrict__ pull_part) {
  const int b   = blockIdx.y;
  const int tid = threadIdx.x;
  __shared__ __align__(16) float s_mean[NLAB * 36];
  __shared__ float s_w[NLAB];
  __shared__ float s_red[4];

  for (int i = tid; i < NLAB * DIM; i += 256) {
    const int l = i >> 5, d = i & 31;
    const float c = gcnt[b * NLAB + l];
    s_mean[l * 36 + d] = gsum[b * (NLAB * DIM) + i] / fmaxf(c, 1.0f);
  }
  if (tid < 64) {
    const float c = (tid < NLAB) ? gcnt[b * NLAB + tid] : 0.f;
    const int pres = (tid >= 1 && tid < NLAB && c > 0.f) ? 1 : 0;
    const unsigned long long bal = __ballot(pres);
    const float n_inst = (float)__popcll(bal);
    if (tid < NLAB)
      s_w[tid] = pres ? 1.f / (fmaxf(c, 1.f) * (n_inst + 1e-6f)) : 0.f;
  }
  __syncthreads();   // drains vmcnt to 0: counted waits below are exact

  const int sub   = tid >> 3;
  const int lane8 = tid & 7;
  const int d0    = lane8 << 2;
  const size_t base = (size_t)b * NPTS;
  const int p0 = blockIdx.x * 32 + sub;
  constexpr int PSTRIDE = BPB2 * 32;            // 4096
  constexpr int NIT     = NPTS / PSTRIDE;       // 32 iterations / thread
  constexpr int NCH     = NIT / CN;             // 4 chunks

  int   labsA[CN], labsB[CN];
  f32x4 eA[CN], eB[CN];
  float wacc = 0.f;

  P2_ISSUE(labsA, eA, 0);
#pragma unroll
  for (int cc = 0; cc < NCH; cc += 2) {
    if (cc + 1 < NCH) P2_ISSUE(labsB, eB, cc + 1);
    if (cc + 1 < NCH) { asm volatile("s_waitcnt vmcnt(16)" ::: "memory"); }
    else              { asm volatile("s_waitcnt vmcnt(0)"  ::: "memory"); }
    __builtin_amdgcn_sched_barrier(0);
    P2_COMPUTE(labsA, eA);
    if (cc + 1 < NCH) {
      if (cc + 2 < NCH) P2_ISSUE(labsA, eA, cc + 2);
      if (cc + 2 < NCH) { asm volatile("s_waitcnt vmcnt(16)" ::: "memory"); }
      else              { asm volatile("s_waitcnt vmcnt(0)"  ::: "memory"); }
      __builtin_amdgcn_sched_barrier(0);
      P2_COMPUTE(labsB, eB);
    }
  }

#pragma unroll
  for (int mm = 1; mm < 64; mm <<= 1) wacc += __shfl_xor(wacc, mm);
  if ((tid & 63) == 0) s_red[tid >> 6] = wacc;
  __syncthreads();
  if (tid == 0)
    pull_part[b * BPB2 + blockIdx.x] =
        s_red[0] + s_red[1] + s_red[2] + s_red[3];
}

// Per-batch push + final combine. One wave per batch, single block.
__global__ __launch_bounds__(512) void finish_kernel(
    const float* __restrict__ gsum, const float* __restrict__ gcnt,
    const float* __restrict__ pull_part, float* __restrict__ out) {
  const int tid = threadIdx.x;
  const int b   = tid >> 6;
  const int t   = tid & 63;
  __shared__ __align__(16) float s_mn[BATCH * 32 * DIM];
  __shared__ float s_ps[BATCH];
  __shared__ float s_pl[BATCH];
  float* mn = s_mn + b * 32 * DIM;

  // pull: wave b reduces its BPB2(=128) block partials
  {
    float plsum = pull_part[b * BPB2 + t] + pull_part[b * BPB2 + 64 + t];
#pragma unroll
    for (int m = 1; m < 64; m <<= 1) plsum += __shfl_xor(plsum, m);
    if (t == 0) s_pl[b] = plsum;
  }

  int pres = 0;
  if (t < 32) {
    const int l = t + 1;
    const float cnt = gcnt[b * NLAB + l];
    pres = (cnt > 0.f) ? 1 : 0;
    const float inv = 1.f / fmaxf(cnt, 1.f);
    float v[DIM];
    float n2 = 0.f;
    for (int d = 0; d < DIM; d++) {
      v[d] = gsum[b * (NLAB * DIM) + l * DIM + d] * inv;
      n2  += v[d] * v[d];
    }
    const float scale = 1.f / fmaxf(sqrtf(n2), 1e-12f);
    for (int d = 0; d < DIM; d++) mn[t * DIM + d] = v[d] * scale;
  }
  const unsigned long long bal = __ballot(pres);
  const unsigned int pmask32 = (unsigned int)(bal & 0xFFFFFFFFull);
  const int n_inst = __popc(pmask32);

  __syncthreads();

  float hp_sum = 0.f, pm_sum = 0.f;
  for (int idx = t; idx < 1024; idx += 64) {
    const int i = idx >> 5, j = idx & 31;
    if (j > i && ((pmask32 >> i) & 1u) && ((pmask32 >> j) & 1u)) {
      const float4* a = (const float4*)(mn + i * DIM);
      const float4* c = (const float4*)(mn + j * DIM);
      float sq = 0.f;
      for (int q = 0; q < 8; q++) {
        const float4 av = a[q], cv = c[q];
        const float dx = av.x - cv.x, dy = av.y - cv.y;
        const float dz = av.z - cv.z, dw = av.w - cv.w;
        sq += dx * dx + dy * dy + dz * dz + dw * dw;
      }
      const float dmat = sqrtf(sq + 1e-24f);
      hp_sum += fmaxf(1.0f - dmat, 0.f);   // 2*DELTA_D = 1.0
      pm_sum += 1.f;
    }
  }
  for (int m = 1; m < 64; m <<= 1) {
    hp_sum += __shfl_xor(hp_sum, m);
    pm_sum += __shfl_xor(pm_sum, m);
  }
  const float push = (n_inst > 1) ? hp_sum / (pm_sum + 1e-6f) : 0.f;
  if (t == 0) s_ps[b] = push;
  __syncthreads();

  if (tid < 64) {
    float pl = (t < BATCH) ? s_pl[t] : 0.f;
    float ps = (t < BATCH) ? s_ps[t] : 0.f;
#pragma unroll
    for (int m = 1; m < 64; m <<= 1) {
      pl += __shfl_xor(pl, m);
      ps += __shfl_xor(ps, m);
    }
    if (t == 0) {
      const float pull_m = pl / (float)BATCH;
      const float push_m = ps / (float)BATCH;
      out[0] = pull_m + push_m;
      out[1] = pull_m;
      out[2] = push_m;
    }
  }
}

extern "C" void kernel_launch(void* const* d_in, const int* in_sizes, int n_in,
                              void* d_out, int out_size, void* d_ws, size_t ws_size,
                              hipStream_t stream) {
  const float* emb = (const float*)d_in[0];
  const int*   lab = (const int*)d_in[1];
  float* out = (float*)d_out;
  float* ws  = (float*)d_ws;

  float* gcnt  = ws + OFF_CNT;
  float* gsum  = ws + OFF_SUM;
  float* pullp = ws + OFF_PULL;
  float* psum  = ws + OFF_PSUM;
  float* pcnt  = ws + OFF_PCNT;

  // only gsum/gcnt need zeroing (reduce_kernel accumulates into them)
  hipMemsetAsync(d_ws, 0, (OFF_SUM + BATCH * NLAB * DIM) * sizeof(float), stream);

  dim3 grid1(G1X, BATCH);
  dim3 gridR((BATCH * NLAB * DIM + BATCH * NLAB + 255) / 256, 8);
  dim3 grid2(BPB2, BATCH);
  pass1_kernel<<<grid1, 256, 0, stream>>>(emb, lab, psum, pcnt);
  reduce_kernel<<<gridR, 256, 0, stream>>>(psum, pcnt, gsum, gcnt);
  pass2_kernel<<<grid2, 256, 0, stream>>>(emb, lab, gsum, gcnt, pullp);
  finish_kernel<<<1, 512, 0, stream>>>(gsum, gcnt, pullp, out);
}

// Round 10
// 232.684 us; speedup vs baseline: 1.5606x; 1.5606x over previous
//
#include <hip/hip_runtime.h>
#include <hip/hip_bf16.h>

#define BATCH 8
#define NPTS  131072
#define DIM   32
#define NLAB  33
#define G1X   128             // pass1 blocks per batch -> 1024 blocks, 8 tiles/wave
#define P1PTS 1024            // points per pass1 block (256 per wave)
#define BPB2  128             // pass2 blocks per batch

// ws float layout
#define OFF_CNT   0                                   // gcnt: BATCH*NLAB = 264
#define OFF_SUM   264                                 // gsum: BATCH*NLAB*DIM = 8448
#define OFF_PULL  (264 + 8448)                        // pull partials: BATCH*BPB2 = 1024
#define OFF_PSUM  (OFF_PULL + BATCH * BPB2)           // pass1 sum partials: 8*128*1056
#define OFF_PCNT  (OFF_PSUM + BATCH * G1X * NLAB * DIM)  // pass1 cnt partials: 8*128*33
#define WS_FLOATS (OFF_PCNT + BATCH * G1X * NLAB)

typedef short  bf16x8 __attribute__((ext_vector_type(8)));
typedef float  f32x4  __attribute__((ext_vector_type(4)));
typedef int    i32x4  __attribute__((ext_vector_type(4)));

static __device__ __forceinline__ short f2bf(float f) {
  __hip_bfloat16 h = __float2bfloat16(f);
  return *reinterpret_cast<short*>(&h);
}

// Pass 1: sums[l][d] = onehot(labels)^T @ E via MFMA one-hot GEMM.
// R14 = R13 with the compile fix: w must be readfirstlane'd so ebase/lbase
// are provably wave-uniform -> SGPR-pair saddr for the asm "s" constraint
// (R13 dropped it; clang materialized the base in a VGPR pair -> invalid
// operand). The R13 theory is unchanged and still untested:
// (a) __shfl label broadcast (8 ds_bpermute + lgkmcnt + dependent chain
//     per tile) -> each lane loads its OWN 8 labels via 2x dwordx4
//     (contiguous ints; g-group duplicates are L2 broadcast);
// (b) 2-deep pipeline (600cy exposed stall/tile) -> 3-deep round-robin
//     A/B/C (18 loads/tile, steady wait vmcnt(36) = 2 tiles in flight).
#define P1_ISSUE(EV, L0, L1, T)                                               \
  {                                                                           \
    const int vt = ve0 + (T) * 4096;                                          \
    const int vl = vl0 + (T) * 128;                                           \
    asm volatile("global_load_dword %0, %1, %2"            : "=&v"(EV[0])  : "v"(vt), "s"(ebase)); \
    asm volatile("global_load_dword %0, %1, %2 offset:128" : "=&v"(EV[1])  : "v"(vt), "s"(ebase)); \
    asm volatile("global_load_dword %0, %1, %2 offset:256" : "=&v"(EV[2])  : "v"(vt), "s"(ebase)); \
    asm volatile("global_load_dword %0, %1, %2 offset:384" : "=&v"(EV[3])  : "v"(vt), "s"(ebase)); \
    asm volatile("global_load_dword %0, %1, %2 offset:512" : "=&v"(EV[4])  : "v"(vt), "s"(ebase)); \
    asm volatile("global_load_dword %0, %1, %2 offset:640" : "=&v"(EV[5])  : "v"(vt), "s"(ebase)); \
    asm volatile("global_load_dword %0, %1, %2 offset:768" : "=&v"(EV[6])  : "v"(vt), "s"(ebase)); \
    asm volatile("global_load_dword %0, %1, %2 offset:896" : "=&v"(EV[7])  : "v"(vt), "s"(ebase)); \
    asm volatile("global_load_dword %0, %1, %2 offset:64"  : "=&v"(EV[8])  : "v"(vt), "s"(ebase)); \
    asm volatile("global_load_dword %0, %1, %2 offset:192" : "=&v"(EV[9])  : "v"(vt), "s"(ebase)); \
    asm volatile("global_load_dword %0, %1, %2 offset:320" : "=&v"(EV[10]) : "v"(vt), "s"(ebase)); \
    asm volatile("global_load_dword %0, %1, %2 offset:448" : "=&v"(EV[11]) : "v"(vt), "s"(ebase)); \
    asm volatile("global_load_dword %0, %1, %2 offset:576" : "=&v"(EV[12]) : "v"(vt), "s"(ebase)); \
    asm volatile("global_load_dword %0, %1, %2 offset:704" : "=&v"(EV[13]) : "v"(vt), "s"(ebase)); \
    asm volatile("global_load_dword %0, %1, %2 offset:832" : "=&v"(EV[14]) : "v"(vt), "s"(ebase)); \
    asm volatile("global_load_dword %0, %1, %2 offset:960" : "=&v"(EV[15]) : "v"(vt), "s"(ebase)); \
    asm volatile("global_load_dwordx4 %0, %1, %2"           : "=&v"(L0) : "v"(vl), "s"(lbase));    \
    asm volatile("global_load_dwordx4 %0, %1, %2 offset:16" : "=&v"(L1) : "v"(vl), "s"(lbase));    \
  }

#define P1_COMPUTE(EV, L0, L1)                                                \
  {                                                                           \
    bf16x8 a0, a1, a2, b0, b1;                                                \
    _Pragma("unroll")                                                         \
    for (int j = 0; j < 8; ++j) {                                             \
      const int lj = (j < 4) ? L0[j] : L1[j - 4];                             \
      const int h0 = (lj == m0), h1 = (lj == m0 + 16), h2 = (lj == m0 + 32);  \
      a0[j] = h0 ? (short)0x3F80 : (short)0;                                  \
      a1[j] = h1 ? (short)0x3F80 : (short)0;                                  \
      a2[j] = h2 ? (short)0x3F80 : (short)0;                                  \
      cnt0 += h0; cnt1 += h1; cnt2 += h2;                                     \
      b0[j] = f2bf(EV[j]);                                                    \
      b1[j] = f2bf(EV[8 + j]);                                                \
    }                                                                         \
    acc[0][0] = __builtin_amdgcn_mfma_f32_16x16x32_bf16(a0, b0, acc[0][0], 0, 0, 0); \
    acc[0][1] = __builtin_amdgcn_mfma_f32_16x16x32_bf16(a0, b1, acc[0][1], 0, 0, 0); \
    acc[1][0] = __builtin_amdgcn_mfma_f32_16x16x32_bf16(a1, b0, acc[1][0], 0, 0, 0); \
    acc[1][1] = __builtin_amdgcn_mfma_f32_16x16x32_bf16(a1, b1, acc[1][1], 0, 0, 0); \
    acc[2][0] = __builtin_amdgcn_mfma_f32_16x16x32_bf16(a2, b0, acc[2][0], 0, 0, 0); \
    acc[2][1] = __builtin_amdgcn_mfma_f32_16x16x32_bf16(a2, b1, acc[2][1], 0, 0, 0); \
  }

#define P1_WAIT(N)                                                            \
  asm volatile("s_waitcnt vmcnt(" #N ")" ::: "memory");                       \
  __builtin_amdgcn_sched_barrier(0);

__global__ __launch_bounds__(256) void pass1_kernel(
    const float* __restrict__ emb, const int* __restrict__ lab,
    float* __restrict__ psum, float* __restrict__ pcnt) {
  const int b    = blockIdx.y;
  const int tid  = threadIdx.x;
  const int w    = __builtin_amdgcn_readfirstlane(tid >> 6);   // wave-uniform!
  const int lane = tid & 63;
  const int m0   = lane & 15;      // A row (label in tile) / B col (dim)
  const int g    = lane >> 4;      // k-group

  // LDS only for the one-shot epilogue reduce (not in the hot loop)
  __shared__ float s_stage[4][NLAB * DIM];   // 16.9 KB
  __shared__ int   s_cnt4[4][NLAB];

  const size_t base = (size_t)b * NPTS + (size_t)blockIdx.x * P1PTS
                    + (size_t)w * 256;
  const float* ebase = emb + base * DIM;
  const int*   lbase = lab + base;
  const int ve0 = g * 1024 + m0 * 4;  // bytes: point g*8 (+j imm), dim m0 (+16u imm)
  const int vl0 = g * 32;             // bytes: labels of points g*8..g*8+7

  f32x4 acc[3][2];
#pragma unroll
  for (int t = 0; t < 3; ++t)
#pragma unroll
    for (int u = 0; u < 2; ++u) acc[t][u] = (f32x4){0.f, 0.f, 0.f, 0.f};
  int cnt0 = 0, cnt1 = 0, cnt2 = 0;

  float eA[16], eB[16], eC[16];
  i32x4 lA0, lA1, lB0, lB1, lC0, lC1;

  // 3-deep round-robin: 8 tiles, 18 loads/tile, steady wait = 2 tiles (36)
  P1_ISSUE(eA, lA0, lA1, 0);
  P1_ISSUE(eB, lB0, lB1, 1);
  P1_ISSUE(eC, lC0, lC1, 2);
  P1_WAIT(36); P1_COMPUTE(eA, lA0, lA1); P1_ISSUE(eA, lA0, lA1, 3);
  P1_WAIT(36); P1_COMPUTE(eB, lB0, lB1); P1_ISSUE(eB, lB0, lB1, 4);
  P1_WAIT(36); P1_COMPUTE(eC, lC0, lC1); P1_ISSUE(eC, lC0, lC1, 5);
  P1_WAIT(36); P1_COMPUTE(eA, lA0, lA1); P1_ISSUE(eA, lA0, lA1, 6);
  P1_WAIT(36); P1_COMPUTE(eB, lB0, lB1); P1_ISSUE(eB, lB0, lB1, 7);
  P1_WAIT(36); P1_COMPUTE(eC, lC0, lC1);
  P1_WAIT(18); P1_COMPUTE(eA, lA0, lA1);
  P1_WAIT(0);  P1_COMPUTE(eB, lB0, lB1);

  // counts: reduce across the 4 k-groups (lanes l, l+16, l+32, l+48)
  cnt0 += __shfl_xor(cnt0, 16); cnt0 += __shfl_xor(cnt0, 32);
  cnt1 += __shfl_xor(cnt1, 16); cnt1 += __shfl_xor(cnt1, 32);
  cnt2 += __shfl_xor(cnt2, 16); cnt2 += __shfl_xor(cnt2, 32);
  if (lane < 16)            s_cnt4[w][m0]      = cnt0;
  else if (lane < 32)       s_cnt4[w][m0 + 16] = cnt1;
  if (lane == 32)           s_cnt4[w][32]      = cnt2;

  // dump accumulators as [label][dim]; D row(label) = g*4+r, col = m0(+16u)
  float* st = s_stage[w];
#pragma unroll
  for (int t = 0; t < 2; ++t)
#pragma unroll
    for (int u = 0; u < 2; ++u)
#pragma unroll
      for (int r = 0; r < 4; ++r)
        st[(t * 16 + g * 4 + r) * DIM + m0 + 16 * u] = acc[t][u][r];
  if (lane < 16) {
    st[32 * DIM + m0]      = acc[2][0][0];
    st[32 * DIM + m0 + 16] = acc[2][1][0];
  }
  __syncthreads();

  // cross-wave reduce + PLAIN coalesced partial stores (no atomics)
  const size_t pb = (size_t)b * G1X + blockIdx.x;
  for (int i = tid; i < NLAB * DIM; i += 256) {
    const float v = s_stage[0][i] + s_stage[1][i] + s_stage[2][i] + s_stage[3][i];
    psum[pb * (NLAB * DIM) + i] = v;
  }
  if (tid < NLAB) {
    const int c = s_cnt4[0][tid] + s_cnt4[1][tid] + s_cnt4[2][tid] + s_cnt4[3][tid];
    pcnt[pb * NLAB + tid] = (float)c;
  }
}

// Folds per-block partials into gsum/gcnt. 8-way sliced over blockIdx.y
// (each slice sums G1X/8=16 partials, coalesced; 8 atomics per address).
__global__ __launch_bounds__(256) void reduce_kernel(
    const float* __restrict__ psum, const float* __restrict__ pcnt,
    float* __restrict__ gsum, float* __restrict__ gcnt) {
  constexpr int TOT = BATCH * NLAB * DIM;   // 8448
  constexpr int KS  = G1X / 8;              // 16 partials per slice
  const int slice = blockIdx.y;
  const int o = blockIdx.x * 256 + threadIdx.x;
  if (o < TOT) {
    const int b = o / (NLAB * DIM), i = o - b * (NLAB * DIM);
    const float* src = psum + ((size_t)b * G1X + slice * KS) * (NLAB * DIM) + i;
    float a0 = 0.f, a1 = 0.f, a2 = 0.f, a3 = 0.f;
#pragma unroll
    for (int k = 0; k < KS; k += 4) {
      a0 += src[(size_t)(k + 0) * (NLAB * DIM)];
      a1 += src[(size_t)(k + 1) * (NLAB * DIM)];
      a2 += src[(size_t)(k + 2) * (NLAB * DIM)];
      a3 += src[(size_t)(k + 3) * (NLAB * DIM)];
    }
    atomicAdd(&gsum[o], (a0 + a1) + (a2 + a3));
  } else if (o - TOT < BATCH * NLAB) {
    const int o2 = o - TOT;
    const int b = o2 / NLAB, l = o2 - b * NLAB;
    const float* src = pcnt + ((size_t)b * G1X + slice * KS) * NLAB + l;
    float a = 0.f;
#pragma unroll
    for (int k = 0; k < KS; ++k) a += src[(size_t)k * NLAB];
    atomicAdd(&gcnt[o2], a);
  }
}

// Pass 2: per-point hinge, streaming pipeline, NO ATOMICS. (unchanged R9)
#define CN 8                       // points per chunk
#define P2_ISSUE(LB, EB, C)                                                   \
  {                                                                           \
    _Pragma("unroll")                                                         \
    for (int j = 0; j < CN; ++j) {                                            \
      const size_t it = (size_t)(C) * CN + j;                                 \
      const unsigned long long al =                                           \
          (unsigned long long)(lab + base + p0 + it * PSTRIDE);               \
      asm volatile("global_load_dword %0, %1, off" : "=&v"(LB[j]) : "v"(al)); \
    }                                                                         \
    _Pragma("unroll")                                                         \
    for (int j = 0; j < CN; ++j) {                                            \
      const size_t it = (size_t)(C) * CN + j;                                 \
      const unsigned long long ae =                                           \
          (unsigned long long)(emb + (base + p0 + it * PSTRIDE) * DIM + d0);  \
      asm volatile("global_load_dwordx4 %0, %1, off" : "=&v"(EB[j]) : "v"(ae)); \
    }                                                                         \
  }

#define P2_COMPUTE(LB, EB)                                                    \
  {                                                                           \
    float s[CN];                                                              \
    _Pragma("unroll")                                                         \
    for (int j = 0; j < CN; ++j) {                                            \
      const f32x4 mv = *(const f32x4*)(s_mean + LB[j] * 36 + d0);             \
      const float dx = EB[j][0] - mv[0], dy = EB[j][1] - mv[1];               \
      const float dz = EB[j][2] - mv[2], dw = EB[j][3] - mv[3];               \
      s[j] = dx * dx + dy * dy + dz * dz + dw * dw;                           \
    }                                                                         \
    _Pragma("unroll")                                                         \
    for (int j = 0; j < CN; ++j) {                                            \
      s[j] += __shfl_xor(s[j], 1);                                            \
      s[j] += __shfl_xor(s[j], 2);                                            \
      s[j] += __shfl_xor(s[j], 4);                                            \
    }                                                                         \
    float sv = s[0];                                                          \
    int   lv = LB[0];                                                         \
    _Pragma("unroll")                                                         \
    for (int j = 1; j < CN; ++j) {                                            \
      sv = (lane8 == j) ? s[j] : sv;                                          \
      lv = (lane8 == j) ? LB[j] : lv;                                         \
    }                                                                         \
    const float dist = sqrtf(sv + 1e-24f);                                    \
    wacc += s_w[lv] * fmaxf(dist - 0.1f, 0.f);                                \
  }

__global__ __launch_bounds__(256, 4) void pass2_kernel(
    const float* __restrict__ emb, const int* __restrict__ lab,
    const float* __restrict__ gsum, const float* __restrict__ gcnt,
    float* __restrict__ pull_part) {
  const int b   = blockIdx.y;
  const int tid = threadIdx.x;
  __shared__ __align__(16) float s_mean[NLAB * 36];
  __shared__ float s_w[NLAB];
  __shared__ float s_red[4];

  for (int i = tid; i < NLAB * DIM; i += 256) {
    const int l = i >> 5, d = i & 31;
    const float c = gcnt[b * NLAB + l];
    s_mean[l * 36 + d] = gsum[b * (NLAB * DIM) + i] / fmaxf(c, 1.0f);
  }
  if (tid < 64) {
    const float c = (tid < NLAB) ? gcnt[b * NLAB + tid] : 0.f;
    const int pres = (tid >= 1 && tid < NLAB && c > 0.f) ? 1 : 0;
    const unsigned long long bal = __ballot(pres);
    const float n_inst = (float)__popcll(bal);
    if (tid < NLAB)
      s_w[tid] = pres ? 1.f / (fmaxf(c, 1.f) * (n_inst + 1e-6f)) : 0.f;
  }
  __syncthreads();   // drains vmcnt to 0: counted waits below are exact

  const int sub   = tid >> 3;
  const int lane8 = tid & 7;
  const int d0    = lane8 << 2;
  const size_t base = (size_t)b * NPTS;
  const int p0 = blockIdx.x * 32 + sub;
  constexpr int PSTRIDE = BPB2 * 32;            // 4096
  constexpr int NIT     = NPTS / PSTRIDE;       // 32 iterations / thread
  constexpr int NCH     = NIT / CN;             // 4 chunks

  int   labsA[CN], labsB[CN];
  f32x4 eA[CN], eB[CN];
  float wacc = 0.f;

  P2_ISSUE(labsA, eA, 0);
#pragma unroll
  for (int cc = 0; cc < NCH; cc += 2) {
    if (cc + 1 < NCH) P2_ISSUE(labsB, eB, cc + 1);
    if (cc + 1 < NCH) { asm volatile("s_waitcnt vmcnt(16)" ::: "memory"); }
    else              { asm volatile("s_waitcnt vmcnt(0)"  ::: "memory"); }
    __builtin_amdgcn_sched_barrier(0);
    P2_COMPUTE(labsA, eA);
    if (cc + 1 < NCH) {
      if (cc + 2 < NCH) P2_ISSUE(labsA, eA, cc + 2);
      if (cc + 2 < NCH) { asm volatile("s_waitcnt vmcnt(16)" ::: "memory"); }
      else              { asm volatile("s_waitcnt vmcnt(0)"  ::: "memory"); }
      __builtin_amdgcn_sched_barrier(0);
      P2_COMPUTE(labsB, eB);
    }
  }

#pragma unroll
  for (int mm = 1; mm < 64; mm <<= 1) wacc += __shfl_xor(wacc, mm);
  if ((tid & 63) == 0) s_red[tid >> 6] = wacc;
  __syncthreads();
  if (tid == 0)
    pull_part[b * BPB2 + blockIdx.x] =
        s_red[0] + s_red[1] + s_red[2] + s_red[3];
}

// Per-batch push + final combine. One wave per batch, single block.
__global__ __launch_bounds__(512) void finish_kernel(
    const float* __restrict__ gsum, const float* __restrict__ gcnt,
    const float* __restrict__ pull_part, float* __restrict__ out) {
  const int tid = threadIdx.x;
  const int b   = tid >> 6;
  const int t   = tid & 63;
  __shared__ __align__(16) float s_mn[BATCH * 32 * DIM];
  __shared__ float s_ps[BATCH];
  __shared__ float s_pl[BATCH];
  float* mn = s_mn + b * 32 * DIM;

  // pull: wave b reduces its BPB2(=128) block partials
  {
    float plsum = pull_part[b * BPB2 + t] + pull_part[b * BPB2 + 64 + t];
#pragma unroll
    for (int m = 1; m < 64; m <<= 1) plsum += __shfl_xor(plsum, m);
    if (t == 0) s_pl[b] = plsum;
  }

  int pres = 0;
  if (t < 32) {
    const int l = t + 1;
    const float cnt = gcnt[b * NLAB + l];
    pres = (cnt > 0.f) ? 1 : 0;
    const float inv = 1.f / fmaxf(cnt, 1.f);
    float v[DIM];
    float n2 = 0.f;
    for (int d = 0; d < DIM; d++) {
      v[d] = gsum[b * (NLAB * DIM) + l * DIM + d] * inv;
      n2  += v[d] * v[d];
    }
    const float scale = 1.f / fmaxf(sqrtf(n2), 1e-12f);
    for (int d = 0; d < DIM; d++) mn[t * DIM + d] = v[d] * scale;
  }
  const unsigned long long bal = __ballot(pres);
  const unsigned int pmask32 = (unsigned int)(bal & 0xFFFFFFFFull);
  const int n_inst = __popc(pmask32);

  __syncthreads();

  float hp_sum = 0.f, pm_sum = 0.f;
  for (int idx = t; idx < 1024; idx += 64) {
    const int i = idx >> 5, j = idx & 31;
    if (j > i && ((pmask32 >> i) & 1u) && ((pmask32 >> j) & 1u)) {
      const float4* a = (const float4*)(mn + i * DIM);
      const float4* c = (const float4*)(mn + j * DIM);
      float sq = 0.f;
      for (int q = 0; q < 8; q++) {
        const float4 av = a[q], cv = c[q];
        const float dx = av.x - cv.x, dy = av.y - cv.y;
        const float dz = av.z - cv.z, dw = av.w - cv.w;
        sq += dx * dx + dy * dy + dz * dz + dw * dw;
      }
      const float dmat = sqrtf(sq + 1e-24f);
      hp_sum += fmaxf(1.0f - dmat, 0.f);   // 2*DELTA_D = 1.0
      pm_sum += 1.f;
    }
  }
  for (int m = 1; m < 64; m <<= 1) {
    hp_sum += __shfl_xor(hp_sum, m);
    pm_sum += __shfl_xor(pm_sum, m);
  }
  const float push = (n_inst > 1) ? hp_sum / (pm_sum + 1e-6f) : 0.f;
  if (t == 0) s_ps[b] = push;
  __syncthreads();

  if (tid < 64) {
    float pl = (t < BATCH) ? s_pl[t] : 0.f;
    float ps = (t < BATCH) ? s_ps[t] : 0.f;
#pragma unroll
    for (int m = 1; m < 64; m <<= 1) {
      pl += __shfl_xor(pl, m);
      ps += __shfl_xor(ps, m);
    }
    if (t == 0) {
      const float pull_m = pl / (float)BATCH;
      const float push_m = ps / (float)BATCH;
      out[0] = pull_m + push_m;
      out[1] = pull_m;
      out[2] = push_m;
    }
  }
}

extern "C" void kernel_launch(void* const* d_in, const int* in_sizes, int n_in,
                              void* d_out, int out_size, void* d_ws, size_t ws_size,
                              hipStream_t stream) {
  const float* emb = (const float*)d_in[0];
  const int*   lab = (const int*)d_in[1];
  float* out = (float*)d_out;
  float* ws  = (float*)d_ws;

  float* gcnt  = ws + OFF_CNT;
  float* gsum  = ws + OFF_SUM;
  float* pullp = ws + OFF_PULL;
  float* psum  = ws + OFF_PSUM;
  float* pcnt  = ws + OFF_PCNT;

  // only gsum/gcnt need zeroing (reduce_kernel accumulates into them)
  hipMemsetAsync(d_ws, 0, (OFF_SUM + BATCH * NLAB * DIM) * sizeof(float), stream);

  dim3 grid1(G1X, BATCH);
  dim3 gridR((BATCH * NLAB * DIM + BATCH * NLAB + 255) / 256, 8);
  dim3 grid2(BPB2, BATCH);
  pass1_kernel<<<grid1, 256, 0, stream>>>(emb, lab, psum, pcnt);
  reduce_kernel<<<gridR, 256, 0, stream>>>(psum, pcnt, gsum, gcnt);
  pass2_kernel<<<grid2, 256, 0, stream>>>(emb, lab, gsum, gcnt, pullp);
  finish_kernel<<<1, 512, 0, stream>>>(gsum, gcnt, pullp, out);
}